// Round 2
// baseline (188.429 us; speedup 1.0000x reference)
//
#include <hip/hip_runtime.h>
#include <math.h>

// SoftArgmax2D: x (B,C,H,W) f32 -> (B,C,2) f32 coords.
// Math identity: softmax-then-window-then-renormalize == window-local
// exp(x - max) weighted average (global softmax Z cancels; Parzen window
// is 0 beyond dist 5, so only an 11x11 patch around the argmax matters).

#define HH 128
#define WW 128
#define HW_ (HH * WW)

__global__ __launch_bounds__(256) void softargmax2d_kernel(
    const float* __restrict__ x, float* __restrict__ out) {
  const int bc = blockIdx.x;
  const float* __restrict__ base = x + (size_t)bc * HW_;
  const int tid  = threadIdx.x;
  const int lane = tid & 63;
  const int wave = tid >> 6;

  // ---------- Phase 1: block-wide argmax (first-occurrence tie-break) ----------
  float best = -INFINITY;
  int   bidx = HW_;  // sentinel larger than any real index
  const float4* b4 = reinterpret_cast<const float4*>(base);
  #pragma unroll 8
  for (int i = tid; i < HW_ / 4; i += 256) {
    float4 v = b4[i];
    const int i4 = i << 2;
    if (v.x > best) { best = v.x; bidx = i4;     }
    if (v.y > best) { best = v.y; bidx = i4 + 1; }
    if (v.z > best) { best = v.z; bidx = i4 + 2; }
    if (v.w > best) { best = v.w; bidx = i4 + 3; }
  }
  // wave64 butterfly reduce: greater value wins; equal value -> lower index
  #pragma unroll
  for (int off = 32; off >= 1; off >>= 1) {
    float ov = __shfl_xor(best, off, 64);
    int   oi = __shfl_xor(bidx, off, 64);
    if (ov > best || (ov == best && oi < bidx)) { best = ov; bidx = oi; }
  }
  __shared__ float s_val[4];
  __shared__ int   s_idx[4];
  __shared__ float s_max;
  __shared__ int   s_amax;
  if (lane == 0) { s_val[wave] = best; s_idx[wave] = bidx; }
  __syncthreads();
  if (tid == 0) {
    float mv = s_val[0]; int mi = s_idx[0];
    #pragma unroll
    for (int w2 = 1; w2 < 4; ++w2) {
      float ov = s_val[w2]; int oi = s_idx[w2];
      if (ov > mv || (ov == mv && oi < mi)) { mv = ov; mi = oi; }
    }
    s_max = mv; s_amax = mi;
  }
  __syncthreads();
  const float mx   = s_max;
  const int   amax = s_amax;
  const int   ax   = amax & (WW - 1);
  const int   ay   = amax >> 7;

  // ---------- Phase 2: 11x11 Parzen-windowed exp-weighted sums ----------
  float sw = 0.0f, swx = 0.0f, swy = 0.0f;
  if (tid < 121) {
    const int dr = tid / 11 - 5;
    const int dc = tid % 11 - 5;
    const int r = ay + dr, c = ax + dc;
    if (r >= 0 && r < HH && c >= 0 && c < WW) {
      const float d2 = (float)(dr * dr + dc * dc);
      if (d2 < 25.0f) {  // dist==5 -> window weight 0, skip
        const float dist = sqrtf(d2);
        const float d = dist * 0.2f;  // dist / hwidth, hwidth = 5
        float win;
        if (dist <= 2.5f) {
          win = 1.0f - 6.0f * d * d * (1.0f - d);
        } else {
          const float t = 1.0f - d;
          win = 2.0f * t * t * t;
        }
        const float xv = base[r * WW + c];
        const float w  = win * __expf(xv - mx);
        sw  = w;
        swx = w * (float)c;
        swy = w * (float)r;
      }
    }
  }
  #pragma unroll
  for (int off = 32; off >= 1; off >>= 1) {
    sw  += __shfl_xor(sw,  off, 64);
    swx += __shfl_xor(swx, off, 64);
    swy += __shfl_xor(swy, off, 64);
  }
  __shared__ float s_sw[4], s_swx[4], s_swy[4];
  if (lane == 0) { s_sw[wave] = sw; s_swx[wave] = swx; s_swy[wave] = swy; }
  __syncthreads();
  if (tid == 0) {
    const float a  = s_sw[0]  + s_sw[1]  + s_sw[2]  + s_sw[3];
    const float bx = s_swx[0] + s_swx[1] + s_swx[2] + s_swx[3];
    const float by = s_swy[0] + s_swy[1] + s_swy[2] + s_swy[3];
    out[bc * 2 + 0] = bx / a;  // x coord (col)
    out[bc * 2 + 1] = by / a;  // y coord (row)
  }
}

extern "C" void kernel_launch(void* const* d_in, const int* in_sizes, int n_in,
                              void* d_out, int out_size, void* d_ws, size_t ws_size,
                              hipStream_t stream) {
  const float* x = (const float*)d_in[0];
  float* out = (float*)d_out;
  const int bc = in_sizes[0] / HW_;  // B*C channels
  softargmax2d_kernel<<<bc, 256, 0, stream>>>(x, out);
}